// Round 7
// baseline (359.870 us; speedup 1.0000x reference)
//
#include <hip/hip_runtime.h>
#include <hip/hip_bf16.h>

typedef unsigned short u16;
typedef unsigned int u32;
typedef __bf16 bf16x8 __attribute__((ext_vector_type(8)));
typedef float f32x4 __attribute__((ext_vector_type(4)));

#define LDA 136   // buf1 row stride: 128+8 pad, 16B-aligned, non-pow2 banks
#define LDR 72    // relu buffer row stride: 64+8 pad, 16B-aligned (144B)

__device__ __forceinline__ u16 f2b(float f) {
  __bf16 b = (__bf16)f;
  return __builtin_bit_cast(u16, b);
}
__device__ __forceinline__ float b2f(u16 h) {
  u32 u = ((u32)h) << 16;
  return __builtin_bit_cast(float, u);
}
__device__ __forceinline__ u32 pk2(float lo, float hi) {
  return (u32)f2b(lo) | ((u32)f2b(hi) << 16);
}
__device__ __forceinline__ bf16x8 zero8() {
  union { int4 i; bf16x8 v; } u;
  u.i = make_int4(0, 0, 0, 0);
  return u.v;
}
__device__ __forceinline__ f32x4 mfma16(bf16x8 a, bf16x8 b, f32x4 c) {
  return __builtin_amdgcn_mfma_f32_16x16x32_bf16(a, b, c, 0, 0, 0);
}
__device__ __forceinline__ ushort4 pk4(float a, float b, float c, float d) {
  ushort4 r; r.x = f2b(a); r.y = f2b(b); r.z = f2b(c); r.w = f2b(d);
  return r;
}

// Transpose C-layout frag pair {ve=tile 2kk, vo=tile 2kk+1} (row-index -> k):
// output lane(l15,lg) element j = M[row=kk*32+lg*8+j][col=l15].
// Verified R3-R6 (P^T gather and av build passed absmax).
__device__ __forceinline__ bf16x8 gatherB(const f32x4& ve, const f32x4& vo,
                                          bool odd_valid, float scale,
                                          int l15, int lg) {
  u32 pe0 = pk2(ve[0] * scale, ve[1] * scale);
  u32 pe1 = pk2(ve[2] * scale, ve[3] * scale);
  u32 po0 = 0, po1 = 0;
  if (odd_valid) {
    po0 = pk2(vo[0] * scale, vo[1] * scale);
    po1 = pk2(vo[2] * scale, vo[3] * scale);
  }
  int s0 = ((lg & 1) * 2) * 16 + l15;
  u32 a0 = __shfl(pe0, s0),      a1 = __shfl(pe1, s0);
  u32 a2 = __shfl(pe0, s0 + 16), a3 = __shfl(pe1, s0 + 16);
  u32 b0 = __shfl(po0, s0),      b1 = __shfl(po1, s0);
  u32 b2 = __shfl(po0, s0 + 16), b3 = __shfl(po1, s0 + 16);
  union { u32 u[4]; bf16x8 v; } fr;
  bool lo = (lg < 2);
  fr.u[0] = lo ? a0 : b0; fr.u[1] = lo ? a1 : b1;
  fr.u[2] = lo ? a2 : b2; fr.u[3] = lo ? a3 : b3;
  return fr.v;
}

// Build K A-frag (16 rows s=l15, k=e 0..15 zero-padded to 32) from packed
// swapped-GEMM output kp = {pk2(e0,e1), pk2(e2,e3)} held at lane(l15, e>>2).
// Target lane(l15,lg<2) u32 r holds e = lg*8+2r, lg*8+2r+1:
//   source lane = (2*lg + (r>>1))*16 + l15, u32 index r&1. Same-column shfl.
__device__ __forceinline__ bf16x8 buildK(u32 k0, u32 k1, int l15, int lg) {
  int lgc = lg & 1;                    // keep shfl src in range for lg>=2
  u32 r0 = __shfl(k0, (2 * lgc + 0) * 16 + l15);
  u32 r1 = __shfl(k1, (2 * lgc + 0) * 16 + l15);
  u32 r2 = __shfl(k0, (2 * lgc + 1) * 16 + l15);
  u32 r3 = __shfl(k1, (2 * lgc + 1) * 16 + l15);
  union { u32 u[4]; bf16x8 v; } fr;
  bool lo = (lg < 2);
  fr.u[0] = lo ? r0 : 0; fr.u[1] = lo ? r1 : 0;
  fr.u[2] = lo ? r2 : 0; fr.u[3] = lo ? r3 : 0;
  return fr.v;
}

// ---------------- weight prep ----------------
// ws (u16): WqT[128][128]@0 (WqT[h*16+e][d]=Wq[h][d][e]), WkT@16384, WvT@32768,
//           WoT@49152 (WoT[n][k]=Wo[k][n]), W1T[512][128]@65536 (W1T[n][k]=W1[k][n]),
//           W2T2[128][512]@131072 (W2T2[c][n]=W2[n][c])
__global__ void prep_kernel(const float* __restrict__ Wq, const float* __restrict__ Wk,
                            const float* __restrict__ Wv, const float* __restrict__ Wo,
                            const float* __restrict__ W1, const float* __restrict__ W2,
                            u16* __restrict__ o) {
  int i = blockIdx.x * 256 + threadIdx.x;
  if (i >= 196608) return;
  float v;
  if (i < 49152) {
    int which = i >> 14, j = i & 16383;
    int n = j >> 7, k = j & 127;
    const float* W = (which == 0) ? Wq : (which == 1) ? Wk : Wv;
    v = W[((n >> 4) * 128 + k) * 16 + (n & 15)];
  } else if (i < 65536) {
    int j = i - 49152;
    v = Wo[(j & 127) * 128 + (j >> 7)];
  } else if (i < 131072) {
    int j = i - 65536;
    v = W1[(j & 127) * 512 + (j >> 7)];
  } else {
    int j = i - 131072;
    int c = j >> 9, n = j & 511;
    v = W2[n * 128 + c];
  }
  o[i] = f2b(v);
}

// ---------------- fused transformer block ----------------
// 8 waves, 52 KB LDS -> 3 blocks/CU (6 waves/SIMD). One full buffer carries
// h -> Q -> O(in-place) -> x1 -> h2; K lives in packed regs (shfl-rebuilt
// A-frags); relu bounces through a small [128][72] chunk buffer.
__global__ void __launch_bounds__(512, 6)
tblock_kernel(const float* __restrict__ xg, const u16* __restrict__ wts,
              const float* __restrict__ bo, const float* __restrict__ b1,
              const float* __restrict__ b2, const float* __restrict__ g1,
              const float* __restrict__ be1, const float* __restrict__ g2,
              const float* __restrict__ be2, float* __restrict__ out) {
  extern __shared__ u16 sm[];
  u16* buf1 = sm;                 // [128][LDA]
  u16* bufr = sm + 128 * LDA;     // [128][LDR]

  const int tid  = threadIdx.x;
  const int w    = tid >> 6;
  const int lane = tid & 63;
  const int l15  = lane & 15;
  const int lg   = lane >> 4;
  const int tr0  = (w >> 2) * 64;    // row half for Wo/FFN
  const int cb   = (w & 3) * 32;     // 32-col group for Wo/FFN outputs
  const int cw   = w & 3;            // 16-col tile inside FFN W1 chunk

  const u16* WqT  = wts;
  const u16* WkT  = wts + 16384;
  const u16* WvT  = wts + 32768;
  const u16* WoT  = wts + 49152;
  const u16* W1T  = wts + 65536;
  const u16* W2T2 = wts + 131072;

  const float* xp = xg + (size_t)blockIdx.x * 16384;
  float*       op = out + (size_t)blockIdx.x * 16384;

  const f32x4 zf4 = {0.f, 0.f, 0.f, 0.f};
  const bf16x8 zb8 = zero8();

  // ---- LN1 (transposed-reg): wave w owns rows w*16..+15; float4 x loads
  {
    const int t = w * 16 + l15;
    float v[8][4];
    #pragma unroll
    for (int nt = 0; nt < 8; ++nt) {
      float4 f = *(const float4*)(xp + t * 128 + nt * 16 + lg * 4);
      v[nt][0] = f.x; v[nt][1] = f.y; v[nt][2] = f.z; v[nt][3] = f.w;
    }
    float s = 0.f;
    #pragma unroll
    for (int nt = 0; nt < 8; ++nt)
      #pragma unroll
      for (int r = 0; r < 4; ++r) s += v[nt][r];
    s += __shfl_xor(s, 16); s += __shfl_xor(s, 32);
    float mu = s * 0.0078125f;
    float vv = 0.f;
    #pragma unroll
    for (int nt = 0; nt < 8; ++nt)
      #pragma unroll
      for (int r = 0; r < 4; ++r) { float d = v[nt][r] - mu; vv += d * d; }
    vv += __shfl_xor(vv, 16); vv += __shfl_xor(vv, 32);
    float rs = rsqrtf(vv * 0.0078125f + 1e-5f);
    #pragma unroll
    for (int nt = 0; nt < 8; ++nt) {
      float4 gv = *(const float4*)(g1 + nt * 16 + lg * 4);
      float4 bv = *(const float4*)(be1 + nt * 16 + lg * 4);
      *(ushort4*)(buf1 + t * LDA + nt * 16 + lg * 4) =
          pk4((v[nt][0] - mu) * rs * gv.x + bv.x, (v[nt][1] - mu) * rs * gv.y + bv.y,
              (v[nt][2] - mu) * rs * gv.z + bv.z, (v[nt][3] - mu) * rs * gv.w + bv.w);
    }
  }
  __syncthreads();   // [bar1] h complete

  // ---- V pass (wave w = head w): av[4] = V^T A-frags via gatherB, no LDS out
  bf16x8 av[4];
  {
    bf16x8 wv[4];
    #pragma unroll
    for (int kk = 0; kk < 4; ++kk)
      wv[kk] = *(const bf16x8*)(WvT + (w * 16 + l15) * 128 + kk * 32 + lg * 8);
    f32x4 vprev = zf4;
    #pragma unroll
    for (int mt = 0; mt < 8; ++mt) {
      f32x4 va = zf4;
      #pragma unroll
      for (int kk = 0; kk < 4; ++kk)
        va = mfma16(*(const bf16x8*)(buf1 + (mt * 16 + l15) * LDA + kk * 32 + lg * 8),
                    wv[kk], va);          // normal: D[t][e]
      if (mt & 1) av[mt >> 1] = gatherB(vprev, va, true, 1.f, l15, lg);
      else        vprev = va;
    }
  }

  // ---- K pass (swapped): kp[st] = packed K^T[e][s] fragments, regs only
  u32 kp[8][2];
  {
    bf16x8 wk[4];
    #pragma unroll
    for (int kk = 0; kk < 4; ++kk)
      wk[kk] = *(const bf16x8*)(WkT + (w * 16 + l15) * 128 + kk * 32 + lg * 8);
    #pragma unroll
    for (int st = 0; st < 8; ++st) {
      f32x4 ka = zf4;
      #pragma unroll
      for (int kk = 0; kk < 4; ++kk)
        ka = mfma16(wk[kk],
                    *(const bf16x8*)(buf1 + (st * 16 + l15) * LDA + kk * 32 + lg * 8),
                    ka);                  // swapped: D[e][s]
      kp[st][0] = pk2(ka[0], ka[1]);
      kp[st][1] = pk2(ka[2], ka[3]);
    }
  }

  // ---- Q pass (swapped): qp packed, stored to buf1 after h dies
  u32 qp[8][2];
  {
    bf16x8 wq[4];
    #pragma unroll
    for (int kk = 0; kk < 4; ++kk)
      wq[kk] = *(const bf16x8*)(WqT + (w * 16 + l15) * 128 + kk * 32 + lg * 8);
    #pragma unroll
    for (int mt = 0; mt < 8; ++mt) {
      f32x4 qa = zf4;
      #pragma unroll
      for (int kk = 0; kk < 4; ++kk)
        qa = mfma16(wq[kk],
                    *(const bf16x8*)(buf1 + (mt * 16 + l15) * LDA + kk * 32 + lg * 8),
                    qa);
      qp[mt][0] = pk2(qa[0], qa[1]);
      qp[mt][1] = pk2(qa[2], qa[3]);
    }
  }
  __syncthreads();   // [bar2] all h reads done -> buf1 reusable

  // ---- Q -> buf1 own column stripe (wave-private from here to Wo)
  #pragma unroll
  for (int mt = 0; mt < 8; ++mt) {
    union { u32 u[2]; ushort4 s; } uq;
    uq.u[0] = qp[mt][0]; uq.u[1] = qp[mt][1];
    *(ushort4*)(buf1 + (mt * 16 + l15) * LDA + w * 16 + lg * 4) = uq.s;
  }

  // ---- attention: S^T = mfma(K,Q); lane owns q-row t = mt*16+l15
  #pragma unroll 1
  for (int mt = 0; mt < 8; ++mt) {
    bf16x8 aq = zb8;
    if (lg < 2)
      aq = *(const bf16x8*)(buf1 + (mt * 16 + l15) * LDA + w * 16 + lg * 8);

    f32x4 sacc[8];
    #pragma unroll
    for (int st = 0; st < 8; ++st) {
      if (st <= mt) {
        bf16x8 bk = buildK(kp[st][0], kp[st][1], l15, lg);
        sacc[st] = mfma16(bk, aq, zf4);
      } else {
        sacc[st] = zf4;
      }
    }

    float mx = -3.0e38f;
    #pragma unroll
    for (int st = 0; st < 8; ++st) if (st <= mt) {
      #pragma unroll
      for (int rg = 0; rg < 4; ++rg) {
        float sv = sacc[st][rg] * 0.25f;
        bool ok = (st < mt) || ((lg * 4 + rg) <= l15);
        sv = ok ? sv : -1.0e30f;
        sacc[st][rg] = sv;
        mx = fmaxf(mx, sv);
      }
    }
    mx = fmaxf(mx, __shfl_xor(mx, 16));
    mx = fmaxf(mx, __shfl_xor(mx, 32));
    float sum = 0.f;
    #pragma unroll
    for (int st = 0; st < 8; ++st) if (st <= mt) {
      #pragma unroll
      for (int rg = 0; rg < 4; ++rg) {
        float e = __expf(sacc[st][rg] - mx);
        sacc[st][rg] = e;
        sum += e;
      }
    }
    sum += __shfl_xor(sum, 16);
    sum += __shfl_xor(sum, 32);
    float inv = 1.f / sum;

    f32x4 oa = zf4;
    #pragma unroll
    for (int kk = 0; kk < 4; ++kk) if (kk <= (mt >> 1)) {
      bf16x8 fr = gatherB(sacc[2 * kk], sacc[2 * kk + 1], (2 * kk + 1) <= mt, inv, l15, lg);
      oa = mfma16(av[kk], fr, oa);      // D[e][t]: lane rg = O[t=l15][e=lg*4+rg]
    }
    // O over the just-consumed Q stripe (within-wave WAR)
    *(ushort4*)(buf1 + (mt * 16 + l15) * LDA + w * 16 + lg * 4) =
        pk4(oa[0], oa[1], oa[2], oa[3]);
  }
  __syncthreads();   // [bar3] all O[t][e] in buf1

  // ---- Wo (swapped, 2x4 tiles) + residual: oacc = x1 (b2 added at epilogue)
  f32x4 oacc[4][2];
  {
    bf16x8 wo[2][4];
    #pragma unroll
    for (int ct = 0; ct < 2; ++ct)
      #pragma unroll
      for (int kk = 0; kk < 4; ++kk)
        wo[ct][kk] = *(const bf16x8*)(WoT + (cb + ct * 16 + l15) * 128 + kk * 32 + lg * 8);
    #pragma unroll
    for (int mt = 0; mt < 4; ++mt) {
      const int t = tr0 + mt * 16 + l15;
      bf16x8 ofr[4];
      #pragma unroll
      for (int kk = 0; kk < 4; ++kk)
        ofr[kk] = *(const bf16x8*)(buf1 + t * LDA + kk * 32 + lg * 8);
      #pragma unroll
      for (int ct = 0; ct < 2; ++ct) {
        f32x4 acc = zf4;
        #pragma unroll
        for (int kk = 0; kk < 4; ++kk)
          acc = mfma16(wo[ct][kk], ofr[kk], acc);
        float4 xv  = *(const float4*)(xp + t * 128 + cb + ct * 16 + lg * 4);
        float4 bov = *(const float4*)(bo + cb + ct * 16 + lg * 4);
        oacc[mt][ct][0] = acc[0] + bov.x + xv.x;
        oacc[mt][ct][1] = acc[1] + bov.y + xv.y;
        oacc[mt][ct][2] = acc[2] + bov.z + xv.z;
        oacc[mt][ct][3] = acc[3] + bov.w + xv.w;
      }
    }
  }
  __syncthreads();   // [bar4] O reads done -> x1 may overwrite

  // ---- x1 (bf16) over O in buf1
  #pragma unroll
  for (int mt = 0; mt < 4; ++mt) {
    const int t = tr0 + mt * 16 + l15;
    #pragma unroll
    for (int ct = 0; ct < 2; ++ct)
      *(ushort4*)(buf1 + t * LDA + cb + ct * 16 + lg * 4) =
          pk4(oacc[mt][ct][0], oacc[mt][ct][1], oacc[mt][ct][2], oacc[mt][ct][3]);
  }
  __syncthreads();   // [bar5] x1 complete

  // ---- LN2 (transposed-reg, in-place): wave w rows w*16..+15
  {
    const int t = w * 16 + l15;
    float v[8][4];
    #pragma unroll
    for (int nt = 0; nt < 8; ++nt) {
      ushort4 u = *(const ushort4*)(buf1 + t * LDA + nt * 16 + lg * 4);
      v[nt][0] = b2f(u.x); v[nt][1] = b2f(u.y); v[nt][2] = b2f(u.z); v[nt][3] = b2f(u.w);
    }
    float s = 0.f;
    #pragma unroll
    for (int nt = 0; nt < 8; ++nt)
      #pragma unroll
      for (int r = 0; r < 4; ++r) s += v[nt][r];
    s += __shfl_xor(s, 16); s += __shfl_xor(s, 32);
    float mu = s * 0.0078125f;
    float vv = 0.f;
    #pragma unroll
    for (int nt = 0; nt < 8; ++nt)
      #pragma unroll
      for (int r = 0; r < 4; ++r) { float d = v[nt][r] - mu; vv += d * d; }
    vv += __shfl_xor(vv, 16); vv += __shfl_xor(vv, 32);
    float rs = rsqrtf(vv * 0.0078125f + 1e-5f);
    #pragma unroll
    for (int nt = 0; nt < 8; ++nt) {
      float4 gv = *(const float4*)(g2 + nt * 16 + lg * 4);
      float4 bv = *(const float4*)(be2 + nt * 16 + lg * 4);
      *(ushort4*)(buf1 + t * LDA + nt * 16 + lg * 4) =
          pk4((v[nt][0] - mu) * rs * gv.x + bv.x, (v[nt][1] - mu) * rs * gv.y + bv.y,
              (v[nt][2] - mu) * rs * gv.z + bv.z, (v[nt][3] - mu) * rs * gv.w + bv.w);
    }
  }
  __syncthreads();   // [bar6] h2 complete

  // ---- FFN: 8 chunks of 64 inner cols; relu bounce through bufr
  #pragma unroll 1
  for (int c8 = 0; c8 < 8; ++c8) {
    bf16x8 w1f[4];
    #pragma unroll
    for (int kk = 0; kk < 4; ++kk)
      w1f[kk] = *(const bf16x8*)(W1T + (c8 * 64 + cw * 16 + l15) * 128 + kk * 32 + lg * 8);
    float4 b1v = *(const float4*)(b1 + c8 * 64 + cw * 16 + lg * 4);
    #pragma unroll
    for (int tt = 0; tt < 4; ++tt) {
      const int t = tr0 + tt * 16 + l15;
      f32x4 fa = zf4;
      #pragma unroll
      for (int kk = 0; kk < 4; ++kk)
        fa = mfma16(w1f[kk],
                    *(const bf16x8*)(buf1 + t * LDA + kk * 32 + lg * 8), fa);
      *(ushort4*)(bufr + t * LDR + cw * 16 + lg * 4) =
          pk4(fmaxf(fa[0] + b1v.x, 0.f), fmaxf(fa[1] + b1v.y, 0.f),
              fmaxf(fa[2] + b1v.z, 0.f), fmaxf(fa[3] + b1v.w, 0.f));
    }
    __syncthreads();   // chunk published

    bf16x8 w2f[2][2];
    #pragma unroll
    for (int ct = 0; ct < 2; ++ct)
      #pragma unroll
      for (int kk = 0; kk < 2; ++kk)
        w2f[ct][kk] = *(const bf16x8*)(W2T2 + (cb + ct * 16 + l15) * 512 + c8 * 64 + kk * 32 + lg * 8);
    #pragma unroll
    for (int mt = 0; mt < 4; ++mt) {
      const int t = tr0 + mt * 16 + l15;
      bf16x8 rf[2];
      #pragma unroll
      for (int kk = 0; kk < 2; ++kk)
        rf[kk] = *(const bf16x8*)(bufr + t * LDR + kk * 32 + lg * 8);
      #pragma unroll
      for (int ct = 0; ct < 2; ++ct)
        #pragma unroll
        for (int kk = 0; kk < 2; ++kk)
          oacc[mt][ct] = mfma16(w2f[ct][kk], rf[kk], oacc[mt][ct]);
    }
    __syncthreads();   // chunk reads done (next chunk may overwrite)
  }

  // ---- epilogue: out = oacc (x1 + ffn) + b2, float4 stores
  #pragma unroll
  for (int mt = 0; mt < 4; ++mt) {
    const int t = tr0 + mt * 16 + l15;
    #pragma unroll
    for (int ct = 0; ct < 2; ++ct) {
      float4 b2v = *(const float4*)(b2 + cb + ct * 16 + lg * 4);
      float4 st;
      st.x = oacc[mt][ct][0] + b2v.x;
      st.y = oacc[mt][ct][1] + b2v.y;
      st.z = oacc[mt][ct][2] + b2v.z;
      st.w = oacc[mt][ct][3] + b2v.w;
      *(float4*)(op + t * 128 + cb + ct * 16 + lg * 4) = st;
    }
  }
}

extern "C" void kernel_launch(void* const* d_in, const int* in_sizes, int n_in,
                              void* d_out, int out_size, void* d_ws, size_t ws_size,
                              hipStream_t stream) {
  const float* x   = (const float*)d_in[0];
  const float* Wq  = (const float*)d_in[1];
  const float* Wk  = (const float*)d_in[2];
  const float* Wv  = (const float*)d_in[3];
  const float* Wo  = (const float*)d_in[4];
  const float* bo  = (const float*)d_in[5];
  const float* W1  = (const float*)d_in[6];
  const float* b1  = (const float*)d_in[7];
  const float* W2  = (const float*)d_in[8];
  const float* b2  = (const float*)d_in[9];
  const float* g1  = (const float*)d_in[10];
  const float* be1 = (const float*)d_in[11];
  const float* g2  = (const float*)d_in[12];
  const float* be2 = (const float*)d_in[13];
  u16* wts = (u16*)d_ws;

  prep_kernel<<<768, 256, 0, stream>>>(Wq, Wk, Wv, Wo, W1, W2, wts);

  const int smem_bytes = (128 * LDA + 128 * LDR) * 2;  // 53248 -> 3 blocks/CU
  hipFuncSetAttribute(reinterpret_cast<const void*>(tblock_kernel),
                      hipFuncAttributeMaxDynamicSharedMemorySize, smem_bytes);
  tblock_kernel<<<1024, 512, smem_bytes, stream>>>(x, wts, bo, b1, b2, g1, be1, g2,
                                                   be2, (float*)d_out);
}

// Round 8
// 175.209 us; speedup vs baseline: 2.0539x; 2.0539x over previous
//
#include <hip/hip_runtime.h>
#include <hip/hip_bf16.h>

typedef unsigned short u16;
typedef unsigned int u32;
typedef __bf16 bf16x8 __attribute__((ext_vector_type(8)));
typedef float f32x4 __attribute__((ext_vector_type(4)));

#define LDA 136   // row stride: 128+8 pad, 16B-aligned (272B), 2-way banks (free)

__device__ __forceinline__ u16 f2b(float f) {
  __bf16 b = (__bf16)f;
  return __builtin_bit_cast(u16, b);
}
__device__ __forceinline__ float b2f(u16 h) {
  u32 u = ((u32)h) << 16;
  return __builtin_bit_cast(float, u);
}
__device__ __forceinline__ u32 pk2(float lo, float hi) {
  return (u32)f2b(lo) | ((u32)f2b(hi) << 16);
}
__device__ __forceinline__ bf16x8 zero8() {
  union { int4 i; bf16x8 v; } u;
  u.i = make_int4(0, 0, 0, 0);
  return u.v;
}
__device__ __forceinline__ f32x4 mfma16(bf16x8 a, bf16x8 b, f32x4 c) {
  return __builtin_amdgcn_mfma_f32_16x16x32_bf16(a, b, c, 0, 0, 0);
}
__device__ __forceinline__ ushort4 pk4(float a, float b, float c, float d) {
  ushort4 r; r.x = f2b(a); r.y = f2b(b); r.z = f2b(c); r.w = f2b(d);
  return r;
}

// Transpose C-layout frag pair {ve=tile 2kk, vo=tile 2kk+1} (row-index -> k):
// output lane(l15,lg) element j = M[row=kk*32+lg*8+j][col=l15].
// Verified R3-R7.
__device__ __forceinline__ bf16x8 gatherB(const f32x4& ve, const f32x4& vo,
                                          bool odd_valid, float scale,
                                          int l15, int lg) {
  u32 pe0 = pk2(ve[0] * scale, ve[1] * scale);
  u32 pe1 = pk2(ve[2] * scale, ve[3] * scale);
  u32 po0 = 0, po1 = 0;
  if (odd_valid) {
    po0 = pk2(vo[0] * scale, vo[1] * scale);
    po1 = pk2(vo[2] * scale, vo[3] * scale);
  }
  int s0 = ((lg & 1) * 2) * 16 + l15;
  u32 a0 = __shfl(pe0, s0),      a1 = __shfl(pe1, s0);
  u32 a2 = __shfl(pe0, s0 + 16), a3 = __shfl(pe1, s0 + 16);
  u32 b0 = __shfl(po0, s0),      b1 = __shfl(po1, s0);
  u32 b2 = __shfl(po0, s0 + 16), b3 = __shfl(po1, s0 + 16);
  union { u32 u[4]; bf16x8 v; } fr;
  bool lo = (lg < 2);
  fr.u[0] = lo ? a0 : b0; fr.u[1] = lo ? a1 : b1;
  fr.u[2] = lo ? a2 : b2; fr.u[3] = lo ? a3 : b3;
  return fr.v;
}

// Build K/Q A-frag (16 rows = l15 column of the packed source, k = e 0..15
// zero-padded to 32) from packed swapped-GEMM output {k0,k1} at lane(l15, e>>2).
// Same-column shuffle. Verified R7 (absmax passed).
__device__ __forceinline__ bf16x8 buildK(u32 k0, u32 k1, int l15, int lg) {
  int lgc = lg & 1;
  u32 r0 = __shfl(k0, (2 * lgc + 0) * 16 + l15);
  u32 r1 = __shfl(k1, (2 * lgc + 0) * 16 + l15);
  u32 r2 = __shfl(k0, (2 * lgc + 1) * 16 + l15);
  u32 r3 = __shfl(k1, (2 * lgc + 1) * 16 + l15);
  union { u32 u[4]; bf16x8 v; } fr;
  bool lo = (lg < 2);
  fr.u[0] = lo ? r0 : 0; fr.u[1] = lo ? r1 : 0;
  fr.u[2] = lo ? r2 : 0; fr.u[3] = lo ? r3 : 0;
  return fr.v;
}

// ---------------- weight prep ----------------
// ws (u16): WqT[128][128]@0 (WqT[h*16+e][d]=Wq[h][d][e]), WkT@16384, WvT@32768,
//           WoT@49152 (WoT[n][k]=Wo[k][n]), W1T[512][128]@65536 (W1T[n][k]=W1[k][n]),
//           W2T2[128][512]@131072 (W2T2[c][n]=W2[n][c])
__global__ void prep_kernel(const float* __restrict__ Wq, const float* __restrict__ Wk,
                            const float* __restrict__ Wv, const float* __restrict__ Wo,
                            const float* __restrict__ W1, const float* __restrict__ W2,
                            u16* __restrict__ o) {
  int i = blockIdx.x * 256 + threadIdx.x;
  if (i >= 196608) return;
  float v;
  if (i < 49152) {
    int which = i >> 14, j = i & 16383;
    int n = j >> 7, k = j & 127;
    const float* W = (which == 0) ? Wq : (which == 1) ? Wk : Wv;
    v = W[((n >> 4) * 128 + k) * 16 + (n & 15)];
  } else if (i < 65536) {
    int j = i - 49152;
    v = Wo[(j & 127) * 128 + (j >> 7)];
  } else if (i < 131072) {
    int j = i - 65536;
    v = W1[(j & 127) * 512 + (j >> 7)];
  } else {
    int j = i - 131072;
    int c = j >> 9, n = j & 511;
    v = W2[n * 128 + c];
  }
  o[i] = f2b(v);
}

// ---------------- fused transformer block ----------------
// 8 waves, 69.6 KB LDS, 2 blocks/CU, launch_bounds(512,4) (no register cap
// pathology — R7 lesson). buf1: h -> x1 -> h2. buf2: Q -> O(in-place) -> relu.
// K lives in registers (buildK shuffles); the bar1..post-attention region is
// barrier-free (all Q/aq/O accesses are wave-private column stripes).
__global__ void __launch_bounds__(512, 4)
tblock_kernel(const float* __restrict__ xg, const u16* __restrict__ wts,
              const float* __restrict__ bo, const float* __restrict__ b1,
              const float* __restrict__ b2, const float* __restrict__ g1,
              const float* __restrict__ be1, const float* __restrict__ g2,
              const float* __restrict__ be2, float* __restrict__ out) {
  extern __shared__ u16 sm[];
  u16* buf1 = sm;                 // [128][LDA] h -> x1 -> h2
  u16* buf2 = sm + 128 * LDA;     // [128][LDA] Q -> O -> relu chunks

  const int tid  = threadIdx.x;
  const int w    = tid >> 6;
  const int lane = tid & 63;
  const int l15  = lane & 15;
  const int lg   = lane >> 4;
  const int tr0  = (w >> 2) * 64;    // row half for Wo/FFN
  const int cb   = (w & 3) * 32;     // 32-col group for Wo/FFN outputs

  const u16* WqT  = wts;
  const u16* WkT  = wts + 16384;
  const u16* WvT  = wts + 32768;
  const u16* WoT  = wts + 49152;
  const u16* W1T  = wts + 65536;
  const u16* W2T2 = wts + 131072;

  const float* xp = xg + (size_t)blockIdx.x * 16384;
  float*       op = out + (size_t)blockIdx.x * 16384;

  const f32x4 zf4 = {0.f, 0.f, 0.f, 0.f};
  const bf16x8 zb8 = zero8();

  // ---- LN1 (transposed-reg): wave w owns rows w*16..+15; float4 x loads
  {
    const int t = w * 16 + l15;
    float v[8][4];
    #pragma unroll
    for (int nt = 0; nt < 8; ++nt) {
      float4 f = *(const float4*)(xp + t * 128 + nt * 16 + lg * 4);
      v[nt][0] = f.x; v[nt][1] = f.y; v[nt][2] = f.z; v[nt][3] = f.w;
    }
    float s = 0.f;
    #pragma unroll
    for (int nt = 0; nt < 8; ++nt)
      #pragma unroll
      for (int r = 0; r < 4; ++r) s += v[nt][r];
    s += __shfl_xor(s, 16); s += __shfl_xor(s, 32);
    float mu = s * 0.0078125f;
    float vv = 0.f;
    #pragma unroll
    for (int nt = 0; nt < 8; ++nt)
      #pragma unroll
      for (int r = 0; r < 4; ++r) { float d = v[nt][r] - mu; vv += d * d; }
    vv += __shfl_xor(vv, 16); vv += __shfl_xor(vv, 32);
    float rs = rsqrtf(vv * 0.0078125f + 1e-5f);
    #pragma unroll
    for (int nt = 0; nt < 8; ++nt) {
      float4 gv = *(const float4*)(g1 + nt * 16 + lg * 4);
      float4 bv = *(const float4*)(be1 + nt * 16 + lg * 4);
      *(ushort4*)(buf1 + t * LDA + nt * 16 + lg * 4) =
          pk4((v[nt][0] - mu) * rs * gv.x + bv.x, (v[nt][1] - mu) * rs * gv.y + bv.y,
              (v[nt][2] - mu) * rs * gv.z + bv.z, (v[nt][3] - mu) * rs * gv.w + bv.w);
    }
  }
  __syncthreads();   // [bar1] h complete — only barrier before attention ends

  // ---- V pass (wave w = head w): av[4] = V^T A-frags via gatherB, regs only
  bf16x8 av[4];
  {
    bf16x8 wv[4];
    #pragma unroll
    for (int kk = 0; kk < 4; ++kk)
      wv[kk] = *(const bf16x8*)(WvT + (w * 16 + l15) * 128 + kk * 32 + lg * 8);
    f32x4 vprev = zf4;
    #pragma unroll
    for (int mt = 0; mt < 8; ++mt) {
      f32x4 va = zf4;
      #pragma unroll
      for (int kk = 0; kk < 4; ++kk)
        va = mfma16(*(const bf16x8*)(buf1 + (mt * 16 + l15) * LDA + kk * 32 + lg * 8),
                    wv[kk], va);          // normal: D[t][e]
      if (mt & 1) av[mt >> 1] = gatherB(vprev, va, true, 1.f, l15, lg);
      else        vprev = va;
    }
  }

  // ---- K+Q fused pass (swapped): one h-read feeds both; K packed -> kp,
  //      Q packed -> own buf2 column stripe (wave-private, no sync needed)
  bf16x8 bk[8];
  {
    u32 kp[8][2];
    {
      bf16x8 wk[4], wq[4];
      #pragma unroll
      for (int kk = 0; kk < 4; ++kk) {
        wk[kk] = *(const bf16x8*)(WkT + (w * 16 + l15) * 128 + kk * 32 + lg * 8);
        wq[kk] = *(const bf16x8*)(WqT + (w * 16 + l15) * 128 + kk * 32 + lg * 8);
      }
      u32 qp[8][2];
      #pragma unroll
      for (int mt = 0; mt < 8; ++mt) {
        bf16x8 hf[4];
        #pragma unroll
        for (int kk = 0; kk < 4; ++kk)
          hf[kk] = *(const bf16x8*)(buf1 + (mt * 16 + l15) * LDA + kk * 32 + lg * 8);
        f32x4 ka = zf4, qa = zf4;
        #pragma unroll
        for (int kk = 0; kk < 4; ++kk) {
          ka = mfma16(wk[kk], hf[kk], ka);   // swapped: D[e][t]
          qa = mfma16(wq[kk], hf[kk], qa);
        }
        kp[mt][0] = pk2(ka[0], ka[1]);
        kp[mt][1] = pk2(ka[2], ka[3]);
        qp[mt][0] = pk2(qa[0], qa[1]);
        qp[mt][1] = pk2(qa[2], qa[3]);
      }
      // Q -> buf2 own column stripe (fully unrolled, static indices)
      #pragma unroll
      for (int mt = 0; mt < 8; ++mt) {
        union { u32 u[2]; ushort4 s; } uq;
        uq.u[0] = qp[mt][0]; uq.u[1] = qp[mt][1];
        *(ushort4*)(buf2 + (mt * 16 + l15) * LDA + w * 16 + lg * 4) = uq.s;
      }
    }
    // build K A-frags once (kp dies here)
    #pragma unroll
    for (int st = 0; st < 8; ++st)
      bk[st] = buildK(kp[st][0], kp[st][1], l15, lg);
  }

  // ---- attention (barrier-free, wave-private): S^T = mfma(K,Q)
  #pragma unroll 1
  for (int mt = 0; mt < 8; ++mt) {
    bf16x8 aq = zb8;
    if (lg < 2)
      aq = *(const bf16x8*)(buf2 + (mt * 16 + l15) * LDA + w * 16 + lg * 8);

    f32x4 sacc[8];
    #pragma unroll
    for (int st = 0; st < 8; ++st)
      sacc[st] = (st <= mt) ? mfma16(bk[st], aq, zf4) : zf4;

    float mx = -3.0e38f;
    #pragma unroll
    for (int st = 0; st < 8; ++st) if (st <= mt) {
      #pragma unroll
      for (int rg = 0; rg < 4; ++rg) {
        float sv = sacc[st][rg] * 0.25f;
        bool ok = (st < mt) || ((lg * 4 + rg) <= l15);
        sv = ok ? sv : -1.0e30f;
        sacc[st][rg] = sv;
        mx = fmaxf(mx, sv);
      }
    }
    mx = fmaxf(mx, __shfl_xor(mx, 16));
    mx = fmaxf(mx, __shfl_xor(mx, 32));
    float sum = 0.f;
    #pragma unroll
    for (int st = 0; st < 8; ++st) if (st <= mt) {
      #pragma unroll
      for (int rg = 0; rg < 4; ++rg) {
        float e = __expf(sacc[st][rg] - mx);
        sacc[st][rg] = e;
        sum += e;
      }
    }
    sum += __shfl_xor(sum, 16);
    sum += __shfl_xor(sum, 32);
    float inv = 1.f / sum;

    f32x4 oa = zf4;
    #pragma unroll
    for (int kk = 0; kk < 4; ++kk) if (kk <= (mt >> 1)) {
      bf16x8 fr = gatherB(sacc[2 * kk], sacc[2 * kk + 1], (2 * kk + 1) <= mt, inv, l15, lg);
      oa = mfma16(av[kk], fr, oa);      // D[e][t]: lane rg = O[t=l15][e=lg*4+rg]
    }
    // O over the just-consumed Q stripe (within-wave WAR)
    *(ushort4*)(buf2 + (mt * 16 + l15) * LDA + w * 16 + lg * 4) =
        pk4(oa[0], oa[1], oa[2], oa[3]);
  }
  __syncthreads();   // [bar2] O published; all h reads done -> buf1 reusable

  // ---- Wo (swapped, 2x4 tiles) + residual: oacc = x1; x1 bf16 -> buf1 over h
  f32x4 oacc[4][2];
  {
    bf16x8 wo[2][4];
    #pragma unroll
    for (int ct = 0; ct < 2; ++ct)
      #pragma unroll
      for (int kk = 0; kk < 4; ++kk)
        wo[ct][kk] = *(const bf16x8*)(WoT + (cb + ct * 16 + l15) * 128 + kk * 32 + lg * 8);
    #pragma unroll
    for (int mt = 0; mt < 4; ++mt) {
      const int t = tr0 + mt * 16 + l15;
      bf16x8 ofr[4];
      #pragma unroll
      for (int kk = 0; kk < 4; ++kk)
        ofr[kk] = *(const bf16x8*)(buf2 + t * LDA + kk * 32 + lg * 8);
      #pragma unroll
      for (int ct = 0; ct < 2; ++ct) {
        f32x4 acc = zf4;
        #pragma unroll
        for (int kk = 0; kk < 4; ++kk)
          acc = mfma16(wo[ct][kk], ofr[kk], acc);
        float4 xv  = *(const float4*)(xp + t * 128 + cb + ct * 16 + lg * 4);
        float4 bov = *(const float4*)(bo + cb + ct * 16 + lg * 4);
        oacc[mt][ct][0] = acc[0] + bov.x + xv.x;
        oacc[mt][ct][1] = acc[1] + bov.y + xv.y;
        oacc[mt][ct][2] = acc[2] + bov.z + xv.z;
        oacc[mt][ct][3] = acc[3] + bov.w + xv.w;
        *(ushort4*)(buf1 + t * LDA + cb + ct * 16 + lg * 4) =
            pk4(oacc[mt][ct][0], oacc[mt][ct][1], oacc[mt][ct][2], oacc[mt][ct][3]);
      }
    }
  }
  __syncthreads();   // [bar3] x1 complete (O reads also done)

  // ---- LN2 (transposed-reg, in-place on buf1): wave w rows w*16..+15
  {
    const int t = w * 16 + l15;
    float v[8][4];
    #pragma unroll
    for (int nt = 0; nt < 8; ++nt) {
      ushort4 u = *(const ushort4*)(buf1 + t * LDA + nt * 16 + lg * 4);
      v[nt][0] = b2f(u.x); v[nt][1] = b2f(u.y); v[nt][2] = b2f(u.z); v[nt][3] = b2f(u.w);
    }
    float s = 0.f;
    #pragma unroll
    for (int nt = 0; nt < 8; ++nt)
      #pragma unroll
      for (int r = 0; r < 4; ++r) s += v[nt][r];
    s += __shfl_xor(s, 16); s += __shfl_xor(s, 32);
    float mu = s * 0.0078125f;
    float vv = 0.f;
    #pragma unroll
    for (int nt = 0; nt < 8; ++nt)
      #pragma unroll
      for (int r = 0; r < 4; ++r) { float d = v[nt][r] - mu; vv += d * d; }
    vv += __shfl_xor(vv, 16); vv += __shfl_xor(vv, 32);
    float rs = rsqrtf(vv * 0.0078125f + 1e-5f);
    #pragma unroll
    for (int nt = 0; nt < 8; ++nt) {
      float4 gv = *(const float4*)(g2 + nt * 16 + lg * 4);
      float4 bv = *(const float4*)(be2 + nt * 16 + lg * 4);
      *(ushort4*)(buf1 + t * LDA + nt * 16 + lg * 4) =
          pk4((v[nt][0] - mu) * rs * gv.x + bv.x, (v[nt][1] - mu) * rs * gv.y + bv.y,
              (v[nt][2] - mu) * rs * gv.z + bv.z, (v[nt][3] - mu) * rs * gv.w + bv.w);
    }
  }
  __syncthreads();   // [bar4] h2 complete

  // ---- FFN (swapped, 2x4 tiles), relu bounce through buf2 per 128-chunk
  {
    #pragma unroll 1
    for (int cc = 0; cc < 4; ++cc) {
      bf16x8 w1f[2][4];
      #pragma unroll
      for (int ct = 0; ct < 2; ++ct)
        #pragma unroll
        for (int kk = 0; kk < 4; ++kk)
          w1f[ct][kk] = *(const bf16x8*)(W1T + (cc * 128 + cb + ct * 16 + l15) * 128 + kk * 32 + lg * 8);
      #pragma unroll
      for (int mt = 0; mt < 4; ++mt) {
        const int t = tr0 + mt * 16 + l15;
        bf16x8 h2f[4];
        #pragma unroll
        for (int kk = 0; kk < 4; ++kk)
          h2f[kk] = *(const bf16x8*)(buf1 + t * LDA + kk * 32 + lg * 8);
        #pragma unroll
        for (int ct = 0; ct < 2; ++ct) {
          f32x4 fa = zf4;
          #pragma unroll
          for (int kk = 0; kk < 4; ++kk)
            fa = mfma16(w1f[ct][kk], h2f[kk], fa);
          float4 bv = *(const float4*)(b1 + cc * 128 + cb + ct * 16 + lg * 4);
          *(ushort4*)(buf2 + t * LDA + cb + ct * 16 + lg * 4) =
              pk4(fmaxf(fa[0] + bv.x, 0.f), fmaxf(fa[1] + bv.y, 0.f),
                  fmaxf(fa[2] + bv.z, 0.f), fmaxf(fa[3] + bv.w, 0.f));
        }
      }
      __syncthreads();   // relu chunk complete

      bf16x8 w2f[2][4];
      #pragma unroll
      for (int ct = 0; ct < 2; ++ct)
        #pragma unroll
        for (int kk = 0; kk < 4; ++kk)
          w2f[ct][kk] = *(const bf16x8*)(W2T2 + (cb + ct * 16 + l15) * 512 + cc * 128 + kk * 32 + lg * 8);
      #pragma unroll
      for (int mt = 0; mt < 4; ++mt) {
        bf16x8 rf[4];
        #pragma unroll
        for (int kk = 0; kk < 4; ++kk)
          rf[kk] = *(const bf16x8*)(buf2 + (tr0 + mt * 16 + l15) * LDA + kk * 32 + lg * 8);
        #pragma unroll
        for (int ct = 0; ct < 2; ++ct)
          #pragma unroll
          for (int kk = 0; kk < 4; ++kk)
            oacc[mt][ct] = mfma16(w2f[ct][kk], rf[kk], oacc[mt][ct]);
      }
      if (cc < 3) __syncthreads();   // relu reads done before overwrite
    }

    // ---- epilogue: out = oacc (x1 + ffn) + b2, float4 stores
    #pragma unroll
    for (int mt = 0; mt < 4; ++mt) {
      const int t = tr0 + mt * 16 + l15;
      #pragma unroll
      for (int ct = 0; ct < 2; ++ct) {
        float4 b2v = *(const float4*)(b2 + cb + ct * 16 + lg * 4);
        float4 st;
        st.x = oacc[mt][ct][0] + b2v.x;
        st.y = oacc[mt][ct][1] + b2v.y;
        st.z = oacc[mt][ct][2] + b2v.z;
        st.w = oacc[mt][ct][3] + b2v.w;
        *(float4*)(op + t * 128 + cb + ct * 16 + lg * 4) = st;
      }
    }
  }
}

extern "C" void kernel_launch(void* const* d_in, const int* in_sizes, int n_in,
                              void* d_out, int out_size, void* d_ws, size_t ws_size,
                              hipStream_t stream) {
  const float* x   = (const float*)d_in[0];
  const float* Wq  = (const float*)d_in[1];
  const float* Wk  = (const float*)d_in[2];
  const float* Wv  = (const float*)d_in[3];
  const float* Wo  = (const float*)d_in[4];
  const float* bo  = (const float*)d_in[5];
  const float* W1  = (const float*)d_in[6];
  const float* b1  = (const float*)d_in[7];
  const float* W2  = (const float*)d_in[8];
  const float* b2  = (const float*)d_in[9];
  const float* g1  = (const float*)d_in[10];
  const float* be1 = (const float*)d_in[11];
  const float* g2  = (const float*)d_in[12];
  const float* be2 = (const float*)d_in[13];
  u16* wts = (u16*)d_ws;

  prep_kernel<<<768, 256, 0, stream>>>(Wq, Wk, Wv, Wo, W1, W2, wts);

  const int smem_bytes = 2 * 128 * LDA * 2;  // 69632 -> 2 blocks/CU
  hipFuncSetAttribute(reinterpret_cast<const void*>(tblock_kernel),
                      hipFuncAttributeMaxDynamicSharedMemorySize, smem_bytes);
  tblock_kernel<<<1024, 512, smem_bytes, stream>>>(x, wts, bo, b1, b2, g1, be1, g2,
                                                   be2, (float*)d_out);
}

// Round 9
// 144.977 us; speedup vs baseline: 2.4823x; 1.2085x over previous
//
#include <hip/hip_runtime.h>
#include <hip/hip_bf16.h>

typedef unsigned short u16;
typedef unsigned int u32;
typedef __bf16 bf16x8 __attribute__((ext_vector_type(8)));
typedef float f32x4 __attribute__((ext_vector_type(4)));

#define LDA 136   // 128+8 bf16 pad: 16B-aligned rows, non-pow2 bank stride

__device__ __forceinline__ u16 f2b(float f) {
  __bf16 b = (__bf16)f;
  return __builtin_bit_cast(u16, b);
}
__device__ __forceinline__ float b2f(u16 h) {
  u32 u = ((u32)h) << 16;
  return __builtin_bit_cast(float, u);
}
__device__ __forceinline__ u32 pk2(float lo, float hi) {
  return (u32)f2b(lo) | ((u32)f2b(hi) << 16);
}
__device__ __forceinline__ bf16x8 zero8() {
  union { int4 i; bf16x8 v; } u;
  u.i = make_int4(0, 0, 0, 0);
  return u.v;
}
__device__ __forceinline__ f32x4 mfma16(bf16x8 a, bf16x8 b, f32x4 c) {
  return __builtin_amdgcn_mfma_f32_16x16x32_bf16(a, b, c, 0, 0, 0);
}
__device__ __forceinline__ ushort4 pk4(float a, float b, float c, float d) {
  ushort4 r; r.x = f2b(a); r.y = f2b(b); r.z = f2b(c); r.w = f2b(d);
  return r;
}

// Transpose C-layout frag pair {ve=tile 2kk, vo=tile 2kk+1} (row-index -> k):
// output lane(l15,lg) element j = M[row=kk*32+lg*8+j][col=l15]. Verified R3-R8.
__device__ __forceinline__ bf16x8 gatherB(const f32x4& ve, const f32x4& vo,
                                          bool odd_valid, float scale,
                                          int l15, int lg) {
  u32 pe0 = pk2(ve[0] * scale, ve[1] * scale);
  u32 pe1 = pk2(ve[2] * scale, ve[3] * scale);
  u32 po0 = 0, po1 = 0;
  if (odd_valid) {
    po0 = pk2(vo[0] * scale, vo[1] * scale);
    po1 = pk2(vo[2] * scale, vo[3] * scale);
  }
  int s0 = ((lg & 1) * 2) * 16 + l15;
  u32 a0 = __shfl(pe0, s0),      a1 = __shfl(pe1, s0);
  u32 a2 = __shfl(pe0, s0 + 16), a3 = __shfl(pe1, s0 + 16);
  u32 b0 = __shfl(po0, s0),      b1 = __shfl(po1, s0);
  u32 b2 = __shfl(po0, s0 + 16), b3 = __shfl(po1, s0 + 16);
  union { u32 u[4]; bf16x8 v; } fr;
  bool lo = (lg < 2);
  fr.u[0] = lo ? a0 : b0; fr.u[1] = lo ? a1 : b1;
  fr.u[2] = lo ? a2 : b2; fr.u[3] = lo ? a3 : b3;
  return fr.v;
}

// ---------------- weight prep (R3 layout) ----------------
// ws (u16): WqT[128][128]@0 (WqT[h*16+e][d]=Wq[h][d][e]), WkT@16384, WvT@32768,
//           WoT@49152 (WoT[n][k]=Wo[k][n]),
//           W1T[512][128]@65536 (W1T[n][k]=W1[k][n]),
//           W2S@131072: [cc][nt][16][128]: W2S[((cc*8+nt)*16+r)*128+c]
//                        = W2[(cc*128+c)*128 + nt*16+r]
__global__ void prep_kernel(const float* __restrict__ Wq, const float* __restrict__ Wk,
                            const float* __restrict__ Wv, const float* __restrict__ Wo,
                            const float* __restrict__ W1, const float* __restrict__ W2,
                            u16* __restrict__ o) {
  int i = blockIdx.x * 256 + threadIdx.x;
  if (i >= 196608) return;
  float v;
  if (i < 49152) {
    int which = i >> 14, j = i & 16383;
    int n = j >> 7, k = j & 127;
    const float* W = (which == 0) ? Wq : (which == 1) ? Wk : Wv;
    v = W[((n >> 4) * 128 + k) * 16 + (n & 15)];
  } else if (i < 65536) {
    int j = i - 49152;
    v = Wo[(j & 127) * 128 + (j >> 7)];
  } else if (i < 131072) {
    int j = i - 65536;
    v = W1[(j & 127) * 512 + (j >> 7)];
  } else {
    int j = i - 131072;
    int c = j & 127, r = (j >> 7) & 15, nt = (j >> 11) & 7, cc = j >> 14;
    v = W2[(cc * 128 + c) * 128 + nt * 16 + r];
  }
  o[i] = f2b(v);
}

// ---------------- fused transformer block (R3 structure + x1-in-oacc) --------
// 2 LDS buffers (69.6 KB -> 2 blocks/CU). Wave w owns output cols w*16..+15 in
// every weight GEMM (weight frags loaded once, reused over 8 row tiles) and
// head w in attention. Residual x1 rides the FFN accumulator.
__global__ void __launch_bounds__(512, 4)
tblock_kernel(const float* __restrict__ xg, const u16* __restrict__ wts,
              const float* __restrict__ bo, const float* __restrict__ b1,
              const float* __restrict__ b2, const float* __restrict__ g1,
              const float* __restrict__ be1, const float* __restrict__ g2,
              const float* __restrict__ be2, float* __restrict__ out) {
  extern __shared__ u16 sm[];
  u16* buf1 = sm;                // h -> x1(bf16) -> h2(in-place)
  u16* buf2 = sm + 128 * LDA;    // K -> Q -> O(in-place) -> relu chunks

  const int tid  = threadIdx.x;
  const int w    = tid >> 6;
  const int lane = tid & 63;
  const int l15  = lane & 15;
  const int lg   = lane >> 4;

  const u16* WqT = wts;
  const u16* WkT = wts + 16384;
  const u16* WvT = wts + 32768;
  const u16* WoT = wts + 49152;
  const u16* W1T = wts + 65536;
  const u16* W2S = wts + 131072;

  const float* xp = xg + (size_t)blockIdx.x * 16384;
  float*       op = out + (size_t)blockIdx.x * 16384;

  const f32x4 zf4 = {0.f, 0.f, 0.f, 0.f};
  const bf16x8 zb8 = zero8();

  // ---- LN1 (transposed-reg, packed; R5-verified): wave w rows w*16..+15
  {
    const int t = w * 16 + l15;
    float v[8][4];
    #pragma unroll
    for (int nt = 0; nt < 8; ++nt) {
      float4 f = *(const float4*)(xp + t * 128 + nt * 16 + lg * 4);
      v[nt][0] = f.x; v[nt][1] = f.y; v[nt][2] = f.z; v[nt][3] = f.w;
    }
    float s = 0.f;
    #pragma unroll
    for (int nt = 0; nt < 8; ++nt)
      #pragma unroll
      for (int r = 0; r < 4; ++r) s += v[nt][r];
    s += __shfl_xor(s, 16); s += __shfl_xor(s, 32);
    float mu = s * 0.0078125f;
    float vv = 0.f;
    #pragma unroll
    for (int nt = 0; nt < 8; ++nt)
      #pragma unroll
      for (int r = 0; r < 4; ++r) { float d = v[nt][r] - mu; vv += d * d; }
    vv += __shfl_xor(vv, 16); vv += __shfl_xor(vv, 32);
    float rs = rsqrtf(vv * 0.0078125f + 1e-5f);
    #pragma unroll
    for (int nt = 0; nt < 8; ++nt) {
      float4 gv = *(const float4*)(g1 + nt * 16 + lg * 4);
      float4 bv = *(const float4*)(be1 + nt * 16 + lg * 4);
      *(ushort4*)(buf1 + t * LDA + nt * 16 + lg * 4) =
          pk4((v[nt][0] - mu) * rs * gv.x + bv.x, (v[nt][1] - mu) * rs * gv.y + bv.y,
              (v[nt][2] - mu) * rs * gv.z + bv.z, (v[nt][3] - mu) * rs * gv.w + bv.w);
    }
  }
  __syncthreads();   // [bar1] h visible to all

  // ---- V GEMM (col-split): av[4] = V^T A-frags via gatherB (vprev pairing)
  bf16x8 av[4];
  {
    bf16x8 bw[4];
    #pragma unroll
    for (int kk = 0; kk < 4; ++kk)
      bw[kk] = *(const bf16x8*)(WvT + (w * 16 + l15) * 128 + kk * 32 + lg * 8);
    f32x4 vprev = zf4;
    #pragma unroll
    for (int mt = 0; mt < 8; ++mt) {
      f32x4 va = zf4;
      #pragma unroll
      for (int kk = 0; kk < 4; ++kk)
        va = mfma16(*(const bf16x8*)(buf1 + (mt * 16 + l15) * LDA + kk * 32 + lg * 8),
                    bw[kk], va);
      if (mt & 1) av[mt >> 1] = gatherB(vprev, va, true, 1.f, l15, lg);
      else        vprev = va;
    }
  }

  // ---- K GEMM -> buf2 own col-stripe as K[t][e] (immediate per-mt store)
  {
    bf16x8 bw[4];
    #pragma unroll
    for (int kk = 0; kk < 4; ++kk)
      bw[kk] = *(const bf16x8*)(WkT + (w * 16 + l15) * 128 + kk * 32 + lg * 8);
    #pragma unroll
    for (int mt = 0; mt < 8; ++mt) {
      f32x4 ka = zf4;
      #pragma unroll
      for (int kk = 0; kk < 4; ++kk)
        ka = mfma16(*(const bf16x8*)(buf1 + (mt * 16 + l15) * LDA + kk * 32 + lg * 8),
                    bw[kk], ka);
      #pragma unroll
      for (int rg = 0; rg < 4; ++rg)
        buf2[(mt * 16 + lg * 4 + rg) * LDA + w * 16 + l15] = f2b(ka[rg]);
    }
  }
  // own-stripe K reads (within-wave RAW, hw-ordered; no barrier needed)
  bf16x8 bk[8];
  #pragma unroll
  for (int st = 0; st < 8; ++st) {
    bk[st] = zb8;
    if (lg < 2)
      bk[st] = *(const bf16x8*)(buf2 + (st * 16 + l15) * LDA + w * 16 + lg * 8);
  }

  // ---- Q GEMM -> same buf2 stripe (within-wave WAR over K; hw-ordered)
  {
    bf16x8 bw[4];
    #pragma unroll
    for (int kk = 0; kk < 4; ++kk)
      bw[kk] = *(const bf16x8*)(WqT + (w * 16 + l15) * 128 + kk * 32 + lg * 8);
    #pragma unroll
    for (int mt = 0; mt < 8; ++mt) {
      f32x4 qa = zf4;
      #pragma unroll
      for (int kk = 0; kk < 4; ++kk)
        qa = mfma16(*(const bf16x8*)(buf1 + (mt * 16 + l15) * LDA + kk * 32 + lg * 8),
                    bw[kk], qa);
      #pragma unroll
      for (int rg = 0; rg < 4; ++rg)
        buf2[(mt * 16 + lg * 4 + rg) * LDA + w * 16 + l15] = f2b(qa[rg]);
    }
  }

  // ---- attention (wave w = head w): S^T = mfma(K,Q); lane owns q-row t=l15
  #pragma unroll 1
  for (int mt = 0; mt < 8; ++mt) {
    bf16x8 aq = zb8;
    if (lg < 2)
      aq = *(const bf16x8*)(buf2 + (mt * 16 + l15) * LDA + w * 16 + lg * 8);

    f32x4 sacc[8];
    #pragma unroll
    for (int st = 0; st < 8; ++st)
      sacc[st] = (st <= mt) ? mfma16(bk[st], aq, zf4) : zf4;

    float mx = -3.0e38f;
    #pragma unroll
    for (int st = 0; st < 8; ++st) if (st <= mt) {
      #pragma unroll
      for (int rg = 0; rg < 4; ++rg) {
        float sv = sacc[st][rg] * 0.25f;
        bool ok = (st < mt) || ((lg * 4 + rg) <= l15);
        sv = ok ? sv : -1.0e30f;
        sacc[st][rg] = sv;
        mx = fmaxf(mx, sv);
      }
    }
    mx = fmaxf(mx, __shfl_xor(mx, 16));
    mx = fmaxf(mx, __shfl_xor(mx, 32));
    float sum = 0.f;
    #pragma unroll
    for (int st = 0; st < 8; ++st) if (st <= mt) {
      #pragma unroll
      for (int rg = 0; rg < 4; ++rg) {
        float e = __expf(sacc[st][rg] - mx);
        sacc[st][rg] = e;
        sum += e;
      }
    }
    sum += __shfl_xor(sum, 16);
    sum += __shfl_xor(sum, 32);
    float inv = 1.f / sum;

    f32x4 oa = zf4;
    #pragma unroll
    for (int kk = 0; kk < 4; ++kk) if (kk <= (mt >> 1)) {
      bf16x8 fr = gatherB(sacc[2 * kk], sacc[2 * kk + 1], (2 * kk + 1) <= mt, inv, l15, lg);
      oa = mfma16(av[kk], fr, oa);   // O^T frag: lane = (e=lg*4+rg, t=l15)
    }
    // O[t][e] over the just-consumed Q stripe (within-wave WAR)
    *(ushort4*)(buf2 + (mt * 16 + l15) * LDA + w * 16 + lg * 4) =
        pk4(oa[0], oa[1], oa[2], oa[3]);
  }
  __syncthreads();   // [bar2] O published; all h reads done -> buf1 reusable

  // ---- Wo GEMM (col-split) + residual: oacc2 = WoO + bo + x + b2 (regs);
  //      x1 bf16 -> buf1 (over dead h) for LN2.
  f32x4 oacc2[8];
  {
    bf16x8 bw[4];
    #pragma unroll
    for (int kk = 0; kk < 4; ++kk)
      bw[kk] = *(const bf16x8*)(WoT + (w * 16 + l15) * 128 + kk * 32 + lg * 8);
    float bov = bo[w * 16 + l15];
    float b2v = b2[w * 16 + l15];
    #pragma unroll
    for (int mt = 0; mt < 8; ++mt) {
      float xrl[4];
      #pragma unroll
      for (int rg = 0; rg < 4; ++rg)
        xrl[rg] = xp[(mt * 16 + lg * 4 + rg) * 128 + w * 16 + l15];
      f32x4 acc = zf4;
      #pragma unroll
      for (int kk = 0; kk < 4; ++kk)
        acc = mfma16(*(const bf16x8*)(buf2 + (mt * 16 + l15) * LDA + kk * 32 + lg * 8),
                     bw[kk], acc);
      #pragma unroll
      for (int rg = 0; rg < 4; ++rg) {
        float x1v = acc[rg] + bov + xrl[rg];
        buf1[(mt * 16 + lg * 4 + rg) * LDA + w * 16 + l15] = f2b(x1v);
        oacc2[mt][rg] = x1v + b2v;     // residual + b2 ride the accumulator
      }
    }
  }
  __syncthreads();   // [bar3] x1(bf16) complete in buf1

  // ---- LN2 (transposed-reg, packed, in-place on buf1): wave w rows w*16..+15
  {
    const int t = w * 16 + l15;
    float v[8][4];
    #pragma unroll
    for (int nt = 0; nt < 8; ++nt) {
      ushort4 u = *(const ushort4*)(buf1 + t * LDA + nt * 16 + lg * 4);
      v[nt][0] = b2f(u.x); v[nt][1] = b2f(u.y); v[nt][2] = b2f(u.z); v[nt][3] = b2f(u.w);
    }
    float s = 0.f;
    #pragma unroll
    for (int nt = 0; nt < 8; ++nt)
      #pragma unroll
      for (int r = 0; r < 4; ++r) s += v[nt][r];
    s += __shfl_xor(s, 16); s += __shfl_xor(s, 32);
    float mu = s * 0.0078125f;
    float vv = 0.f;
    #pragma unroll
    for (int nt = 0; nt < 8; ++nt)
      #pragma unroll
      for (int r = 0; r < 4; ++r) { float d = v[nt][r] - mu; vv += d * d; }
    vv += __shfl_xor(vv, 16); vv += __shfl_xor(vv, 32);
    float rs = rsqrtf(vv * 0.0078125f + 1e-5f);
    #pragma unroll
    for (int nt = 0; nt < 8; ++nt) {
      float4 gv = *(const float4*)(g2 + nt * 16 + lg * 4);
      float4 bv = *(const float4*)(be2 + nt * 16 + lg * 4);
      *(ushort4*)(buf1 + t * LDA + nt * 16 + lg * 4) =
          pk4((v[nt][0] - mu) * rs * gv.x + bv.x, (v[nt][1] - mu) * rs * gv.y + bv.y,
              (v[nt][2] - mu) * rs * gv.z + bv.z, (v[nt][3] - mu) * rs * gv.w + bv.w);
    }
  }
  __syncthreads();   // [bar4] h2 complete

  // ---- FFN (col-split): per cc: W1 tile w -> relu chunk in buf2 -> W2 partial
  #pragma unroll 1
  for (int cc = 0; cc < 4; ++cc) {
    {
      bf16x8 bw1[4];
      #pragma unroll
      for (int kk = 0; kk < 4; ++kk)
        bw1[kk] = *(const bf16x8*)(W1T + (cc * 128 + w * 16 + l15) * 128 + kk * 32 + lg * 8);
      float b1v = b1[cc * 128 + w * 16 + l15];
      #pragma unroll
      for (int mt = 0; mt < 8; ++mt) {
        f32x4 facc = zf4;
        #pragma unroll
        for (int kk = 0; kk < 4; ++kk)
          facc = mfma16(*(const bf16x8*)(buf1 + (mt * 16 + l15) * LDA + kk * 32 + lg * 8),
                        bw1[kk], facc);
        #pragma unroll
        for (int rg = 0; rg < 4; ++rg)
          buf2[(mt * 16 + lg * 4 + rg) * LDA + w * 16 + l15] =
              f2b(fmaxf(facc[rg] + b1v, 0.f));
      }
    }
    __syncthreads();   // relu chunk complete

    {
      bf16x8 bw2[4];
      #pragma unroll
      for (int kk = 0; kk < 4; ++kk)
        bw2[kk] = *(const bf16x8*)(W2S + ((cc * 8 + w) * 16 + l15) * 128 + kk * 32 + lg * 8);
      #pragma unroll
      for (int mt = 0; mt < 8; ++mt)
        #pragma unroll
        for (int kk = 0; kk < 4; ++kk)
          oacc2[mt] = mfma16(*(const bf16x8*)(buf2 + (mt * 16 + l15) * LDA + kk * 32 + lg * 8),
                             bw2[kk], oacc2[mt]);
    }
    if (cc < 3) __syncthreads();   // relu reads done (next cc overwrites)
  }

  // ---- epilogue: out = oacc2 (x1 + b2 + ffn), col-split scalar stores
  #pragma unroll
  for (int mt = 0; mt < 8; ++mt)
    #pragma unroll
    for (int rg = 0; rg < 4; ++rg)
      op[(mt * 16 + lg * 4 + rg) * 128 + w * 16 + l15] = oacc2[mt][rg];
}

extern "C" void kernel_launch(void* const* d_in, const int* in_sizes, int n_in,
                              void* d_out, int out_size, void* d_ws, size_t ws_size,
                              hipStream_t stream) {
  const float* x   = (const float*)d_in[0];
  const float* Wq  = (const float*)d_in[1];
  const float* Wk  = (const float*)d_in[2];
  const float* Wv  = (const float*)d_in[3];
  const float* Wo  = (const float*)d_in[4];
  const float* bo  = (const float*)d_in[5];
  const float* W1  = (const float*)d_in[6];
  const float* b1  = (const float*)d_in[7];
  const float* W2  = (const float*)d_in[8];
  const float* b2  = (const float*)d_in[9];
  const float* g1  = (const float*)d_in[10];
  const float* be1 = (const float*)d_in[11];
  const float* g2  = (const float*)d_in[12];
  const float* be2 = (const float*)d_in[13];
  u16* wts = (u16*)d_ws;

  prep_kernel<<<768, 256, 0, stream>>>(Wq, Wk, Wv, Wo, W1, W2, wts);

  const int smem_bytes = 2 * 128 * LDA * 2;  // 69632 -> 2 blocks/CU
  hipFuncSetAttribute(reinterpret_cast<const void*>(tblock_kernel),
                      hipFuncAttributeMaxDynamicSharedMemorySize, smem_bytes);
  tblock_kernel<<<1024, 512, smem_bytes, stream>>>(x, wts, bo, b1, b2, g1, be1, g2,
                                                   be2, (float*)d_out);
}